// Round 1
// baseline (19029.361 us; speedup 1.0000x reference)
//
#include <hip/hip_runtime.h>
#include <stdint.h>

typedef unsigned long long u64;

#define Bb   8
#define Tt   2048
#define Dd   1280
#define Pp   4
#define Ii   5120
#define Ff   512
#define BFn  4096
#define EPS  1e-5f

#define BK   16
#define LDT  132   // 128 + 4 pad

// sortable key: min over key == min over float (handles negatives)
__device__ __forceinline__ unsigned fkey(float f) {
    unsigned u = __float_as_uint(f);
    return (u & 0x80000000u) ? ~u : (u | 0x80000000u);
}

__device__ __forceinline__ u64 shfl_down_u64(u64 v, int off, int w) {
    unsigned lo = (unsigned)(v & 0xFFFFFFFFull);
    unsigned hi = (unsigned)(v >> 32);
    lo = __shfl_down(lo, off, w);
    hi = __shfl_down(hi, off, w);
    return ((u64)hi << 32) | (u64)lo;
}

// ---------------- codebook row norms ----------------
__global__ __launch_bounds__(256) void norms_kernel(
        const float* __restrict__ cb0, const float* __restrict__ cb1,
        const float* __restrict__ cb2, const float* __restrict__ cb3,
        float* __restrict__ norms) {
    int r = blockIdx.x;
    const float* row;
    if (r < 8192)       row = cb0 + (size_t)r * Ii;
    else if (r < 16384) row = cb1 + (size_t)(r - 8192) * Ii;
    else if (r < 20480) row = cb2 + (size_t)(r - 16384) * Ii;
    else                row = cb3 + (size_t)(r - 20480) * Ii;
    float s = 0.f;
    for (int i = threadIdx.x * 4; i < Ii; i += 1024) {
        float4 v = *(const float4*)(row + i);
        s += v.x * v.x + v.y * v.y + v.z * v.z + v.w * v.w;
    }
    __shared__ float red[4];
    for (int off = 32; off; off >>= 1) s += __shfl_down(s, off, 64);
    if ((threadIdx.x & 63) == 0) red[threadIdx.x >> 6] = s;
    __syncthreads();
    if (threadIdx.x == 0) norms[r] = red[0] + red[1] + red[2] + red[3];
}

// ---------------- Xp[bf][j] = x[b, 4f+(j&3), j>>2]  (j = d*4+k) ----------------
__global__ __launch_bounds__(256) void permute_kernel(
        const float* __restrict__ x, float* __restrict__ Xp) {
    int bf = blockIdx.x;
    int b = bf >> 9, f = bf & 511;
    const float* xrow = x + ((size_t)b * Tt + 4 * f) * Dd;
    float* outp = Xp + (size_t)bf * Ii;
    for (int j = threadIdx.x; j < Ii; j += 256) {
        outp[j] = xrow[(j & 3) * Dd + (j >> 2)];
    }
}

// ---------------- fp32 GEMM: C[m][n] = sum_k A[m][k] * B[n][k] ----------------
__global__ __launch_bounds__(256, 3) void gemm_nt(
        const float* __restrict__ A, const float* __restrict__ Bm,
        float* __restrict__ C, int N, int K) {
    __shared__ float As[BK][LDT];
    __shared__ float Bs[BK][LDT];
    const int m0 = blockIdx.x * 128;
    const int n0 = blockIdx.y * 128;
    const int t  = threadIdx.x;
    const int tx = t & 15, ty = t >> 4;
    const int lrow = t >> 2;
    const int lkc  = (t & 3) << 2;

    const float* Ap0 = A  + (size_t)(m0 + lrow) * K + lkc;
    const float* Ap1 = Ap0 + (size_t)64 * K;
    const float* Bp0 = Bm + (size_t)(n0 + lrow) * K + lkc;
    const float* Bp1 = Bp0 + (size_t)64 * K;

    float acc[8][8];
#pragma unroll
    for (int i = 0; i < 8; ++i)
#pragma unroll
        for (int j = 0; j < 8; ++j) acc[i][j] = 0.f;

    for (int k0 = 0; k0 < K; k0 += BK) {
        float4 a0 = *(const float4*)(Ap0 + k0);
        float4 a1 = *(const float4*)(Ap1 + k0);
        float4 b0 = *(const float4*)(Bp0 + k0);
        float4 b1 = *(const float4*)(Bp1 + k0);
        __syncthreads();
        As[lkc + 0][lrow] = a0.x; As[lkc + 1][lrow] = a0.y;
        As[lkc + 2][lrow] = a0.z; As[lkc + 3][lrow] = a0.w;
        As[lkc + 0][lrow + 64] = a1.x; As[lkc + 1][lrow + 64] = a1.y;
        As[lkc + 2][lrow + 64] = a1.z; As[lkc + 3][lrow + 64] = a1.w;
        Bs[lkc + 0][lrow] = b0.x; Bs[lkc + 1][lrow] = b0.y;
        Bs[lkc + 2][lrow] = b0.z; Bs[lkc + 3][lrow] = b0.w;
        Bs[lkc + 0][lrow + 64] = b1.x; Bs[lkc + 1][lrow + 64] = b1.y;
        Bs[lkc + 2][lrow + 64] = b1.z; Bs[lkc + 3][lrow + 64] = b1.w;
        __syncthreads();
#pragma unroll
        for (int kk = 0; kk < BK; ++kk) {
            float a[8], b[8];
            *(float4*)(a)     = *(const float4*)(&As[kk][ty * 4]);
            *(float4*)(a + 4) = *(const float4*)(&As[kk][ty * 4 + 64]);
            *(float4*)(b)     = *(const float4*)(&Bs[kk][tx * 4]);
            *(float4*)(b + 4) = *(const float4*)(&Bs[kk][tx * 4 + 64]);
#pragma unroll
            for (int i = 0; i < 8; ++i)
#pragma unroll
                for (int j = 0; j < 8; ++j)
                    acc[i][j] = fmaf(a[i], b[j], acc[i][j]);
        }
    }
#pragma unroll
    for (int ih = 0; ih < 2; ++ih)
#pragma unroll
        for (int r = 0; r < 4; ++r) {
            int row = m0 + ih * 64 + ty * 4 + r;
            float* cp = C + (size_t)row * N + n0;
            float4 v;
            v.x = acc[ih * 4 + r][0]; v.y = acc[ih * 4 + r][1];
            v.z = acc[ih * 4 + r][2]; v.w = acc[ih * 4 + r][3];
            *(float4*)(cp + tx * 4) = v;
            v.x = acc[ih * 4 + r][4]; v.y = acc[ih * 4 + r][5];
            v.z = acc[ih * 4 + r][6]; v.w = acc[ih * 4 + r][7];
            *(float4*)(cp + 64 + tx * 4) = v;
        }
}

// ---------------- score GEMM + fused argmin ----------------
// score[m][c] = norms[c] - 2 * dot(res[m], cb[c]);  atomicMin packed (key<<32|c)
__global__ __launch_bounds__(256, 3) void score_argmin(
        const float* __restrict__ A, const float* __restrict__ Bm,
        const float* __restrict__ norms, u64* __restrict__ best, int K) {
    __shared__ float As[BK][LDT];
    __shared__ float Bs[BK][LDT];
    const int m0 = blockIdx.x * 128;
    const int n0 = blockIdx.y * 128;
    const int t  = threadIdx.x;
    const int tx = t & 15, ty = t >> 4;
    const int lrow = t >> 2;
    const int lkc  = (t & 3) << 2;

    const float* Ap0 = A  + (size_t)(m0 + lrow) * K + lkc;
    const float* Ap1 = Ap0 + (size_t)64 * K;
    const float* Bp0 = Bm + (size_t)(n0 + lrow) * K + lkc;
    const float* Bp1 = Bp0 + (size_t)64 * K;

    float acc[8][8];
#pragma unroll
    for (int i = 0; i < 8; ++i)
#pragma unroll
        for (int j = 0; j < 8; ++j) acc[i][j] = 0.f;

    for (int k0 = 0; k0 < K; k0 += BK) {
        float4 a0 = *(const float4*)(Ap0 + k0);
        float4 a1 = *(const float4*)(Ap1 + k0);
        float4 b0 = *(const float4*)(Bp0 + k0);
        float4 b1 = *(const float4*)(Bp1 + k0);
        __syncthreads();
        As[lkc + 0][lrow] = a0.x; As[lkc + 1][lrow] = a0.y;
        As[lkc + 2][lrow] = a0.z; As[lkc + 3][lrow] = a0.w;
        As[lkc + 0][lrow + 64] = a1.x; As[lkc + 1][lrow + 64] = a1.y;
        As[lkc + 2][lrow + 64] = a1.z; As[lkc + 3][lrow + 64] = a1.w;
        Bs[lkc + 0][lrow] = b0.x; Bs[lkc + 1][lrow] = b0.y;
        Bs[lkc + 2][lrow] = b0.z; Bs[lkc + 3][lrow] = b0.w;
        Bs[lkc + 0][lrow + 64] = b1.x; Bs[lkc + 1][lrow + 64] = b1.y;
        Bs[lkc + 2][lrow + 64] = b1.z; Bs[lkc + 3][lrow + 64] = b1.w;
        __syncthreads();
#pragma unroll
        for (int kk = 0; kk < BK; ++kk) {
            float a[8], b[8];
            *(float4*)(a)     = *(const float4*)(&As[kk][ty * 4]);
            *(float4*)(a + 4) = *(const float4*)(&As[kk][ty * 4 + 64]);
            *(float4*)(b)     = *(const float4*)(&Bs[kk][tx * 4]);
            *(float4*)(b + 4) = *(const float4*)(&Bs[kk][tx * 4 + 64]);
#pragma unroll
            for (int i = 0; i < 8; ++i)
#pragma unroll
                for (int j = 0; j < 8; ++j)
                    acc[i][j] = fmaf(a[i], b[j], acc[i][j]);
        }
    }
    // epilogue: per-row argmin over this block's 128 cols
#pragma unroll
    for (int ih = 0; ih < 2; ++ih)
#pragma unroll
        for (int r = 0; r < 4; ++r) {
            int row = m0 + ih * 64 + ty * 4 + r;
            u64 bestv = ~0ull;
#pragma unroll
            for (int j = 0; j < 8; ++j) {
                int col = n0 + ((j < 4) ? (tx * 4 + j) : (64 + tx * 4 + (j - 4)));
                float s = norms[col] - 2.f * acc[ih * 4 + r][j];
                u64 pk = ((u64)fkey(s) << 32) | (u64)(unsigned)col;
                if (pk < bestv) bestv = pk;
            }
#pragma unroll
            for (int off = 8; off; off >>= 1) {
                u64 o = shfl_down_u64(bestv, off, 16);
                if (o < bestv) bestv = o;
            }
            if (tx == 0) atomicMin(&best[row], bestv);
        }
}

// ---------------- h = silu(g) * u, in place over G ----------------
__global__ __launch_bounds__(256) void silu_mul_kernel(
        float* __restrict__ G, const float* __restrict__ U) {
    size_t idx = ((size_t)blockIdx.x * 256 + threadIdx.x) * 4;
    float4 g = *(float4*)(G + idx);
    float4 u = *(const float4*)(U + idx);
    g.x = g.x / (1.f + expf(-g.x)) * u.x;
    g.y = g.y / (1.f + expf(-g.y)) * u.y;
    g.z = g.z / (1.f + expf(-g.z)) * u.z;
    g.w = g.w / (1.f + expf(-g.w)) * u.w;
    *(float4*)(G + idx) = g;
}

// ---------------- layernorm(c + xi) in place; init best ----------------
__global__ __launch_bounds__(256) void ln_init_kernel(
        float* __restrict__ RES, const float* __restrict__ x,
        const float* __restrict__ scale, const float* __restrict__ bias,
        u64* __restrict__ best) {
    __shared__ float row[Ii];
    __shared__ float red[8];
    const int bf = blockIdx.x;
    const int b = bf >> 9, f = bf & 511;
    const float* xrow = x + ((size_t)b * Tt + 4 * f) * Dd;  // frame = 5120 contiguous
    float* r = RES + (size_t)bf * Ii;

    float s = 0.f;
    for (int i = threadIdx.x * 4; i < Ii; i += 1024) {
        float4 c = *(const float4*)(r + i);
        float4 xi = *(const float4*)(xrow + i);
        c.x += xi.x; c.y += xi.y; c.z += xi.z; c.w += xi.w;
        *(float4*)(row + i) = c;
        s += c.x + c.y + c.z + c.w;
    }
    for (int off = 32; off; off >>= 1) s += __shfl_down(s, off, 64);
    if ((threadIdx.x & 63) == 0) red[threadIdx.x >> 6] = s;
    __syncthreads();
    if (threadIdx.x == 0) red[4] = (red[0] + red[1] + red[2] + red[3]) / (float)Ii;
    __syncthreads();
    const float mu = red[4];

    float vs = 0.f;
    for (int i = threadIdx.x * 4; i < Ii; i += 1024) {
        float4 c = *(const float4*)(row + i);
        float dx = c.x - mu, dy = c.y - mu, dz = c.z - mu, dw = c.w - mu;
        vs += dx * dx + dy * dy + dz * dz + dw * dw;
    }
    for (int off = 32; off; off >>= 1) vs += __shfl_down(vs, off, 64);
    if ((threadIdx.x & 63) == 0) red[threadIdx.x >> 6] = vs;
    __syncthreads();
    if (threadIdx.x == 0) {
        float var = (red[0] + red[1] + red[2] + red[3]) / (float)Ii;
        red[5] = 1.0f / sqrtf(var + EPS);
    }
    __syncthreads();
    const float rs = red[5];

    for (int i = threadIdx.x * 4; i < Ii; i += 1024) {
        float4 c = *(const float4*)(row + i);
        float4 sc = *(const float4*)(scale + i);
        float4 bi = *(const float4*)(bias + i);
        c.x = (c.x - mu) * rs * sc.x + bi.x;
        c.y = (c.y - mu) * rs * sc.y + bi.y;
        c.z = (c.z - mu) * rs * sc.z + bi.z;
        c.w = (c.w - mu) * rs * sc.w + bi.w;
        *(float4*)(r + i) = c;
    }
    if (threadIdx.x == 0) best[bf] = ~0ull;
}

// ---------------- emit id, subtract chosen code, re-init best ----------------
__global__ __launch_bounds__(256) void update_kernel(
        float* __restrict__ RES, const float* __restrict__ cb,
        u64* __restrict__ best, int* __restrict__ outp,
        const int* __restrict__ lens, int t, int do_sub) {
    const int bf = blockIdx.x;
    const u64 pk = best[bf];
    __syncthreads();
    const int id = (int)(unsigned)(pk & 0xFFFFFFFFull);
    if (threadIdx.x == 0) {
        int b = bf >> 9, f = bf & 511;
        outp[bf * 4 + t] = (f < lens[b]) ? id : 0;
        best[bf] = ~0ull;
    }
    if (do_sub) {
        const float* e = cb + (size_t)id * Ii;
        float* r = RES + (size_t)bf * Ii;
        for (int i = threadIdx.x * 4; i < Ii; i += 1024) {
            float4 rv = *(float4*)(r + i);
            float4 ev = *(const float4*)(e + i);
            rv.x -= ev.x; rv.y -= ev.y; rv.z -= ev.z; rv.w -= ev.w;
            *(float4*)(r + i) = rv;
        }
    }
}

extern "C" void kernel_launch(void* const* d_in, const int* in_sizes, int n_in,
                              void* d_out, int out_size, void* d_ws, size_t ws_size,
                              hipStream_t stream) {
    const float* x     = (const float*)d_in[0];
    const int*   lens  = (const int*)d_in[1];
    const float* wgate = (const float*)d_in[2];
    const float* wup   = (const float*)d_in[3];
    const float* wdown = (const float*)d_in[4];
    const float* lns   = (const float*)d_in[5];
    const float* lnb   = (const float*)d_in[6];
    const float* cb[4] = {(const float*)d_in[7], (const float*)d_in[8],
                          (const float*)d_in[9], (const float*)d_in[10]};
    int* outp = (int*)d_out;

    const size_t NBF = (size_t)BFn * Ii;     // 20,971,520 floats
    float* buf0  = (float*)d_ws;             // Xp, later RES/residual
    float* buf1  = buf0 + NBF;               // G, later H
    float* buf2  = buf1 + NBF;               // U
    float* norms = buf2 + NBF;               // 24576 floats
    u64*   best  = (u64*)(norms + 24576);    // 4096 u64 (8B-aligned)

    norms_kernel<<<dim3(24576), dim3(256), 0, stream>>>(cb[0], cb[1], cb[2], cb[3], norms);
    permute_kernel<<<dim3(BFn), dim3(256), 0, stream>>>(x, buf0);
    gemm_nt<<<dim3(32, 40), dim3(256), 0, stream>>>(buf0, wgate, buf1, Ii, Ii);
    gemm_nt<<<dim3(32, 40), dim3(256), 0, stream>>>(buf0, wup,   buf2, Ii, Ii);
    silu_mul_kernel<<<dim3((unsigned)(NBF / 1024)), dim3(256), 0, stream>>>(buf1, buf2);
    gemm_nt<<<dim3(32, 40), dim3(256), 0, stream>>>(buf1, wdown, buf0, Ii, Ii);
    ln_init_kernel<<<dim3(BFn), dim3(256), 0, stream>>>(buf0, x, lns, lnb, best);

    const int csz[4] = {8192, 8192, 4096, 4096};
    int noff = 0;
    for (int tcb = 0; tcb < 4; ++tcb) {
        score_argmin<<<dim3(32, csz[tcb] / 128), dim3(256), 0, stream>>>(
            buf0, cb[tcb], norms + noff, best, Ii);
        update_kernel<<<dim3(BFn), dim3(256), 0, stream>>>(
            buf0, cb[tcb], best, outp, lens, tcb, tcb < 3 ? 1 : 0);
        noff += csz[tcb];
    }
    (void)in_sizes; (void)n_in; (void)out_size; (void)ws_size;
}